// Round 13
// baseline (469.218 us; speedup 1.0000x reference)
//
#include <hip/hip_runtime.h>
#include <cstdint>
#include <cstddef>

typedef unsigned short ushort_t;
typedef __attribute__((ext_vector_type(8))) short bf16x8;
typedef __attribute__((ext_vector_type(4))) float f32x4;

// Problem constants
#define PN1   10000
#define PN2   10000
#define NH    8
#define NLAY  2
#define NE12  320000
#define NE21  320000
#define NEF   500000

// ---------- bf16 helpers (RNE) ----------
__device__ __forceinline__ unsigned f2bf(float f) {
  union { float f; unsigned u; } v; v.f = f;
  return (v.u + 0x7FFFu + ((v.u >> 16) & 1u)) >> 16;
}
__device__ __forceinline__ float bf2f(unsigned s) {
  union { float f; unsigned u; } v; v.u = s << 16; return v.f;
}
union U4 { uint4 u; bf16x8 s; };

// ---------- DPP helpers ----------
__device__ __forceinline__ float dpp_red8(float x) {
  int t;
  t = __builtin_amdgcn_update_dpp(0, __float_as_int(x), 0xB1,  0xf, 0xf, true);
  x += __int_as_float(t);
  t = __builtin_amdgcn_update_dpp(0, __float_as_int(x), 0x4E,  0xf, 0xf, true);
  x += __int_as_float(t);
  t = __builtin_amdgcn_update_dpp(0, __float_as_int(x), 0x141, 0xf, 0xf, true);
  x += __int_as_float(t);
  return x;
}
__device__ __forceinline__ float dpp_red4(float x) {
  int t;
  t = __builtin_amdgcn_update_dpp(0, __float_as_int(x), 0xB1, 0xf, 0xf, true);
  x += __int_as_float(t);
  t = __builtin_amdgcn_update_dpp(0, __float_as_int(x), 0x4E, 0xf, 0xf, true);
  x += __int_as_float(t);
  return x;
}
__device__ __forceinline__ float dpp_xor1(float x) {
  return __int_as_float(__builtin_amdgcn_update_dpp(0, __float_as_int(x), 0xB1, 0xf, 0xf, true));
}

// ============================================================================
// MFMA GEMM core: 4 waves, tile 64x128, K=128.
// ============================================================================
#define GB 157   // ceil(10000/64)

__device__ __forceinline__ void stage_A(const float* __restrict__ X, unsigned* sA,
                                        int rowbase, int N, int tid)
{
#pragma unroll
  for (int i = 0; i < 8; ++i) {
    int idx = tid + i * 256;
    int r = idx >> 5;
    int c4 = (idx & 31) << 2;
    int gr = rowbase + r;
    float4 v = make_float4(0.f, 0.f, 0.f, 0.f);
    if (gr < N) v = *(const float4*)(X + (size_t)gr * 128 + c4);
    sA[r * 68 + (c4 >> 1)]     = f2bf(v.x) | (f2bf(v.y) << 16);
    sA[r * 68 + (c4 >> 1) + 1] = f2bf(v.z) | (f2bf(v.w) << 16);
  }
}

__device__ __forceinline__ void stage_B(const unsigned* __restrict__ Wt, unsigned* sB, int tid)
{
#pragma unroll
  for (int i = 0; i < 8; ++i) {
    int idx = tid + i * 256;
    int n = idx >> 4;
    int k4 = (idx & 15) << 2;
    *(uint4*)&sB[n * 68 + k4] = *(const uint4*)&Wt[(size_t)idx << 2];
  }
}

__device__ __forceinline__ void mfma_compute(const unsigned* sA, const unsigned* sB,
                                             int w, int lane, f32x4 acc[8])
{
#pragma unroll
  for (int ks = 0; ks < 4; ++ks) {
    U4 a; a.u = *(const uint4*)&sA[(w * 16 + (lane & 15)) * 68 + ks * 16 + ((lane >> 4) << 2)];
#pragma unroll
    for (int t = 0; t < 8; ++t) {
      U4 b; b.u = *(const uint4*)&sB[(t * 16 + (lane & 15)) * 68 + ks * 16 + ((lane >> 4) << 2)];
      acc[t] = __builtin_amdgcn_mfma_f32_16x16x32_bf16(a.s, b.s, acc[t], 0, 0, 0);
    }
  }
}

// ---------- single-matrix GEMM: mode 0 = relu; mode 2 = skip-blend + cat ----------
__launch_bounds__(256, 2)
__global__ void mfma_gemm1(const float* __restrict__ X1, const float* __restrict__ X2,
                           const unsigned* __restrict__ W1t, const float* __restrict__ b1,
                           const unsigned* __restrict__ W2t, const float* __restrict__ b2,
                           float* __restrict__ Y1, float* __restrict__ Y2,
                           int nb1, int N, int mode,
                           const float* __restrict__ skip1, const float* __restrict__ skip2,
                           ushort_t* __restrict__ cat1, ushort_t* __restrict__ cat2, int catoff)
{
  __shared__ unsigned sA[64 * 68];
  __shared__ unsigned sB[128 * 68];
  const int tid = threadIdx.x;
  const bool t2 = blockIdx.x >= nb1;
  const int rowbase = (t2 ? blockIdx.x - nb1 : blockIdx.x) * 64;
  const float* X = t2 ? X2 : X1;
  const unsigned* Wt = t2 ? W2t : W1t;
  const float* bias = t2 ? b2 : b1;
  float* Y = t2 ? Y2 : Y1;
  ushort_t* cat = t2 ? cat2 : cat1;

  stage_A(X, sA, rowbase, N, tid);
  stage_B(Wt, sB, tid);
  __syncthreads();

  const int w = tid >> 6, lane = tid & 63;
  f32x4 acc[8];
#pragma unroll
  for (int t = 0; t < 8; ++t) acc[t] = (f32x4){0.f, 0.f, 0.f, 0.f};
  mfma_compute(sA, sB, w, lane, acc);

  float beta = 0.f;
  if (mode == 2) beta = 1.0f / (1.0f + expf(-((t2 ? skip2 : skip1)[0])));
  const int cb = lane & 15;
  const int rq = (lane >> 4) << 2;
#pragma unroll
  for (int t = 0; t < 8; ++t) {
    int c = t * 16 + cb;
    float bv = bias[c];
#pragma unroll
    for (int r = 0; r < 4; ++r) {
      int row = rowbase + w * 16 + rq + r;
      float val = acc[t][r] + bv;
      if (mode == 0) {
        if (row < N) Y[(size_t)row * 128 + c] = fmaxf(val, 0.f);
      } else {
        float xo = (row < N) ? Y[(size_t)row * 128 + c] : 0.f;
        float tv = beta * val + (1.f - beta) * xo;
        if (row < N) Y[(size_t)row * 128 + c] = tv;
        float nb = dpp_xor1(tv);
        if (((lane & 1) == 0) && row < N)
          *(unsigned*)(cat + (size_t)row * 256 + catoff + c) = f2bf(tv) | (f2bf(nb) << 16);
      }
    }
  }
}

// ---------- fused K/V/Q projection (3 matrices, shared A) ----------
__launch_bounds__(256, 2)
__global__ void mfma_kvq(const float* __restrict__ X1, const float* __restrict__ X2,
                         const unsigned* __restrict__ WqT1, const unsigned* __restrict__ WkT1,
                         const unsigned* __restrict__ WvT1,
                         const float* __restrict__ bq1, const float* __restrict__ bk1,
                         const float* __restrict__ bv1,
                         const unsigned* __restrict__ WqT2, const unsigned* __restrict__ WkT2,
                         const unsigned* __restrict__ WvT2,
                         const float* __restrict__ bq2, const float* __restrict__ bk2,
                         const float* __restrict__ bv2,
                         float* __restrict__ q1o, unsigned* __restrict__ kv1,
                         float* __restrict__ q2o, unsigned* __restrict__ kv2,
                         int nb1, int N)
{
  __shared__ unsigned sA[64 * 68];
  __shared__ unsigned sB[128 * 68];
  const int tid = threadIdx.x;
  const bool t2 = blockIdx.x >= nb1;
  const int rowbase = (t2 ? blockIdx.x - nb1 : blockIdx.x) * 64;
  const float* X = t2 ? X2 : X1;
  const unsigned* Wt[3] = { t2 ? WqT2 : WqT1, t2 ? WkT2 : WkT1, t2 ? WvT2 : WvT1 };
  const float* bs[3] = { t2 ? bq2 : bq1, t2 ? bk2 : bk1, t2 ? bv2 : bv1 };
  float* qo = t2 ? q2o : q1o;
  unsigned* kvo = t2 ? kv2 : kv1;

  stage_A(X, sA, rowbase, N, tid);
  const int w = tid >> 6, lane = tid & 63;
  const int cb = lane & 15;
  const int rq = (lane >> 4) << 2;

  for (int j = 0; j < 3; ++j) {
    if (j > 0) __syncthreads();
    stage_B(Wt[j], sB, tid);
    __syncthreads();
    f32x4 acc[8];
#pragma unroll
    for (int t = 0; t < 8; ++t) acc[t] = (f32x4){0.f, 0.f, 0.f, 0.f};
    mfma_compute(sA, sB, w, lane, acc);

#pragma unroll
    for (int t = 0; t < 8; ++t) {
      int c = t * 16 + cb;
      float bv = bs[j][c];
#pragma unroll
      for (int r = 0; r < 4; ++r) {
        int row = rowbase + w * 16 + rq + r;
        float val = acc[t][r] + bv;
        if (j == 0) {
          if (row < N) qo[(size_t)row * 128 + c] = val;
        } else {
          float nb = dpp_xor1(val);
          if (((lane & 1) == 0) && row < N) {
            unsigned pk = f2bf(val) | (f2bf(nb) << 16);
            kvo[(size_t)row * 128 + c + (j == 1 ? 0 : 1)] = pk;
          }
        }
      }
    }
  }
}

// ---------- ONE preprocessing kernel ----------
__global__ void prep(const float* W_in1, const float* W_in2,
                     const float* Wq_n1, const float* Wq_n2,
                     const float* Wa_n1, const float* Wa_n2,
                     const float* Wk_n1, const float* bk_n1,
                     const float* Wv_n1, const float* bv_n1,
                     const float* Wk_n2, const float* bk_n2,
                     const float* Wv_n2, const float* bv_n2,
                     const float* a_rel_12, const float* m_rel_12,
                     const float* a_rel_21, const float* m_rel_21,
                     unsigned* WinT1, unsigned* WinT2,
                     unsigned* WqT1, unsigned* WqT2,
                     unsigned* WaT1, unsigned* WaT2,
                     unsigned* WkT1, float* bkF1, unsigned* WvT1, float* bvF1,
                     unsigned* WkT2, float* bkF2, unsigned* WvT2, float* bvF2,
                     int* deg)
{
  const int yid = blockIdx.y;
  int idx = blockIdx.x * 256 + threadIdx.x;

  if (yid < 10) {
    if (idx >= 8192) return;
    const float* W; unsigned* Wt;
    switch (yid) {
      case 0: W = W_in1;          Wt = WinT1;        break;
      case 1: W = W_in2;          Wt = WinT2;        break;
      case 2: W = Wq_n1;          Wt = WqT1;         break;
      case 3: W = Wq_n1 + 16384;  Wt = WqT1 + 8192;  break;
      case 4: W = Wq_n2;          Wt = WqT2;         break;
      case 5: W = Wq_n2 + 16384;  Wt = WqT2 + 8192;  break;
      case 6: W = Wa_n1;          Wt = WaT1;         break;
      case 7: W = Wa_n1 + 16384;  Wt = WaT1 + 8192;  break;
      case 8: W = Wa_n2;          Wt = WaT2;         break;
      default: W = Wa_n2 + 16384; Wt = WaT2 + 8192;  break;
    }
    int n = idx & 127, kp = idx >> 7;
    float a = W[(size_t)(2 * kp) * 128 + n];
    float b = W[(size_t)(2 * kp + 1) * 128 + n];
    Wt[n * 64 + kp] = f2bf(a) | (f2bf(b) << 16);
  } else if (yid < 18) {
    int job = yid - 10;
    int l = job >> 2, m = job & 3;
    const float *W, *b, *rel; unsigned* Wt; float* bf;
    switch (m) {
      case 0:  W = Wk_n1; b = bk_n1; rel = a_rel_12; Wt = WkT1; bf = bkF1; break;
      case 1:  W = Wv_n1; b = bv_n1; rel = m_rel_12; Wt = WvT1; bf = bvF1; break;
      case 2:  W = Wk_n2; b = bk_n2; rel = a_rel_21; Wt = WkT2; bf = bkF2; break;
      default: W = Wv_n2; b = bv_n2; rel = m_rel_21; Wt = WvT2; bf = bvF2; break;
    }
    W += (size_t)l * 16384; b += l * 128; rel += (size_t)l * 2048;
    Wt += (size_t)l * 8192; bf += l * 128;
    if (idx < 8192) {
      int n = idx & 127, kp = idx >> 7;
      int h = n >> 4, e = n & 15;
      const float* rr = rel + h * 256;
      const float* s0 = W + (size_t)(2 * kp) * 128 + h * 16;
      const float* s1 = s0 + 128;
      float a0 = 0.f, a1 = 0.f;
#pragma unroll
      for (int d = 0; d < 16; ++d) {
        float rv = rr[d * 16 + e];
        a0 = fmaf(s0[d], rv, a0);
        a1 = fmaf(s1[d], rv, a1);
      }
      Wt[n * 64 + kp] = f2bf(a0) | (f2bf(a1) << 16);
    } else if (idx < 8320) {
      int n = idx - 8192;
      int h = n >> 4, e = n & 15;
      const float* rr = rel + h * 256;
      float a = 0.f;
#pragma unroll
      for (int d = 0; d < 16; ++d) a = fmaf(b[h * 16 + d], rr[d * 16 + e], a);
      bf[n] = a;
    }
  } else {
    // zero deg12, deg21, deg_f (contiguous, 3 x 10016 ints)
    for (int k = idx; k < 30048; k += 8448) deg[k] = 0;
  }
}

// ---------- CSR build (2 attention graphs + readout m-buckets) ----------
__global__ void csr_hist3(const int* __restrict__ dst12, const int* __restrict__ dst21,
                          const int* __restrict__ mi,
                          int* __restrict__ deg12, int* __restrict__ deg21,
                          int* __restrict__ degF)
{
  int e = blockIdx.x * 256 + threadIdx.x;
  if (e < NE12) atomicAdd(&deg12[dst12[e]], 1);
  if (e < NE21) atomicAdd(&deg21[dst21[e]], 1);
  if (e < NEF)  atomicAdd(&degF[mi[e]], 1);
}

__global__ void csr_scan3(const int* __restrict__ degA, int* __restrict__ rowptrA,
                          int* __restrict__ curA, int NA, int EA,
                          const int* __restrict__ degB, int* __restrict__ rowptrB,
                          int* __restrict__ curB, int NB, int EB,
                          const int* __restrict__ degC, int* __restrict__ rowptrC,
                          int* __restrict__ curC, int NC, int EC)
{
  const int* deg; int* rowptr; int* cursor; int N, E;
  if (blockIdx.x == 0)      { deg = degA; rowptr = rowptrA; cursor = curA; N = NA; E = EA; }
  else if (blockIdx.x == 1) { deg = degB; rowptr = rowptrB; cursor = curB; N = NB; E = EB; }
  else                      { deg = degC; rowptr = rowptrC; cursor = curC; N = NC; E = EC; }
  __shared__ int part[256];
  const int t = threadIdx.x;
  const int chunk = (N + 255) / 256;
  const int b = t * chunk;
  const int e = (b + chunk < N) ? b + chunk : N;
  int s = 0;
  for (int i = b; i < e; ++i) s += deg[i];
  part[t] = s;
  __syncthreads();
  if (t == 0) {
    int run = 0;
    for (int i = 0; i < 256; ++i) { int v = part[i]; part[i] = run; run += v; }
  }
  __syncthreads();
  int run = part[t];
  for (int i = b; i < e; ++i) { rowptr[i] = run; cursor[i] = run; run += deg[i]; }
  if (t == 0) rowptr[N] = E;
}

__global__ void csr_scatter3(const int* __restrict__ src12, const int* __restrict__ dst12,
                             int* __restrict__ cur12, int* __restrict__ csr12,
                             const int* __restrict__ src21, const int* __restrict__ dst21,
                             int* __restrict__ cur21, int* __restrict__ csr21,
                             const int* __restrict__ mi, const int* __restrict__ di,
                             int* __restrict__ curF, int2* __restrict__ csrF)
{
  int e = blockIdx.x * 256 + threadIdx.x;
  if (e < NE12) { int p = atomicAdd(&cur12[dst12[e]], 1); csr12[p] = src12[e]; }
  if (e < NE21) { int p = atomicAdd(&cur21[dst21[e]], 1); csr21[p] = src21[e]; }
  if (e < NEF)  { int p = atomicAdd(&curF[mi[e]], 1); csrF[p] = make_int2(di[e], e); }
}

// ---------- fused gather attention (R12's wide-load, static-index version) ----------
__launch_bounds__(256)
__global__ void attn_gather2(const int* __restrict__ rowptr12, const int* __restrict__ csr12,
                             const float* __restrict__ q2, const unsigned* __restrict__ kv1,
                             const float* __restrict__ pr12,
                             const int* __restrict__ rowptr21, const int* __restrict__ csr21,
                             const float* __restrict__ q1, const unsigned* __restrict__ kv2,
                             const float* __restrict__ pr21,
                             float* __restrict__ agg2, float* __restrict__ agg1)
{
  const int wid = (blockIdx.x * 256 + threadIdx.x) >> 6;
  const int lane = threadIdx.x & 63;
  const int sub = lane >> 5;
  const int sl = lane & 31;
  const bool dirB = wid >= PN2;
  const int d = __builtin_amdgcn_readfirstlane(dirB ? wid - PN2 : wid);
  const int* rowptr = dirB ? rowptr21 : rowptr12;
  const int* csr    = dirB ? csr21 : csr12;
  const float* q    = dirB ? q1 : q2;
  const unsigned* kv = dirB ? kv2 : kv1;
  const float* prel = dirB ? pr21 : pr12;
  float* agg = dirB ? agg1 : agg2;

  const int h = sl >> 2;
  const float4 qv = *(const float4*)(q + (size_t)d * 128 + 4 * sl);
  const float pr2 = prel[h] * (0.25f * 1.4426950408889634f);
  const int beg = __builtin_amdgcn_readfirstlane(rowptr[d]);
  const int end = __builtin_amdgcn_readfirstlane(rowptr[d + 1]);
  const int co = 4 * sl;

  float ssum = 0.f, a0 = 0.f, a1 = 0.f, a2 = 0.f, a3 = 0.f;

  uint4 buf[4];
#pragma unroll
  for (int j = 0; j < 4; ++j) {
    int idx = beg + 2 * j + sub;
    int s = (idx < end) ? csr[idx] : 0;
    buf[j] = *(const uint4*)(kv + (size_t)s * 128 + co);
  }

  for (int i = beg; i < end; i += 8) {
    uint4 cur[4];
#pragma unroll
    for (int j = 0; j < 4; ++j) cur[j] = buf[j];
#pragma unroll
    for (int j = 0; j < 4; ++j) {
      int idx = i + 8 + 2 * j + sub;
      int s = (idx < end) ? csr[idx] : 0;
      buf[j] = *(const uint4*)(kv + (size_t)s * 128 + co);
    }
    float p[4], ex[4];
#pragma unroll
    for (int j = 0; j < 4; ++j) {
      float t = qv.x * bf2f(cur[j].x & 0xffffu);
      t = fmaf(qv.y, bf2f(cur[j].x >> 16), t);
      t = fmaf(qv.z, bf2f(cur[j].z & 0xffffu), t);
      p[j] = fmaf(qv.w, bf2f(cur[j].z >> 16), t);
    }
#pragma unroll
    for (int j = 0; j < 4; ++j) p[j] = dpp_red4(p[j]);
#pragma unroll
    for (int j = 0; j < 4; ++j)
      ex[j] = (i + 2 * j + sub < end) ? exp2f(p[j] * pr2) : 0.f;
    ssum += (ex[0] + ex[1]) + (ex[2] + ex[3]);
#pragma unroll
    for (int j = 0; j < 4; ++j) {
      a0 = fmaf(ex[j], bf2f(cur[j].y & 0xffffu), a0);
      a1 = fmaf(ex[j], bf2f(cur[j].y >> 16),     a1);
      a2 = fmaf(ex[j], bf2f(cur[j].w & 0xffffu), a2);
      a3 = fmaf(ex[j], bf2f(cur[j].w >> 16),     a3);
    }
  }

  ssum += __shfl_xor(ssum, 32);
  a0 += __shfl_xor(a0, 32);
  a1 += __shfl_xor(a1, 32);
  a2 += __shfl_xor(a2, 32);
  a3 += __shfl_xor(a3, 32);

  if (sub == 0) {
    const float inv = 1.0f / (ssum + 1e-16f);
    float o0 = a0 * inv, o1 = a1 * inv, o2 = a2 * inv, o3 = a3 * inv;
    o0 = 0.5f * o0 * (1.f + erff(o0 * 0.70710678118654752f));
    o1 = 0.5f * o1 * (1.f + erff(o1 * 0.70710678118654752f));
    o2 = 0.5f * o2 * (1.f + erff(o2 * 0.70710678118654752f));
    o3 = 0.5f * o3 * (1.f + erff(o3 * 0.70710678118654752f));
    float4 out; out.x = o0; out.y = o1; out.z = o2; out.w = o3;
    *(float4*)(agg + (size_t)d * 128 + co) = out;
  }
}

// ---------- m-bucketed readout: one wave per m-node, Em in registers ----------
// 8-lane groups each process one query edge of this m: gather Ed row only.
// Per-edge fp32 math is bit-identical to the old edge_dot_bf (same channel
// split per lane, same fma order, same dpp_red8).
__device__ __forceinline__ void edm_load(const int2* __restrict__ csrF,
                                         const ushort_t* __restrict__ Ed,
                                         int idx, int end, int g, int gl,
                                         int2& dsc, uint4 (&bu)[4])
{
  int2 v = make_int2(0, -1);
  int p = idx + g;
  if (p < end) v = csrF[p];
  dsc = v;
  const uint4* B = (const uint4*)(Ed + (size_t)v.x * 256);
#pragma unroll
  for (int i = 0; i < 4; ++i) bu[i] = B[gl + 8 * i];
}

__device__ __forceinline__ void edm_compute(const uint4 (&em)[4], const int2 dsc,
                                            const uint4 (&bu)[4], int gl,
                                            float* __restrict__ y)
{
  float acc = 0.f;
#pragma unroll
  for (int i = 0; i < 4; ++i) {
    uint4 a = em[i], b = bu[i];
    acc = fmaf(bf2f(a.x & 0xffffu), bf2f(b.x & 0xffffu), acc);
    acc = fmaf(bf2f(a.x >> 16),     bf2f(b.x >> 16),     acc);
    acc = fmaf(bf2f(a.y & 0xffffu), bf2f(b.y & 0xffffu), acc);
    acc = fmaf(bf2f(a.y >> 16),     bf2f(b.y >> 16),     acc);
    acc = fmaf(bf2f(a.z & 0xffffu), bf2f(b.z & 0xffffu), acc);
    acc = fmaf(bf2f(a.z >> 16),     bf2f(b.z >> 16),     acc);
    acc = fmaf(bf2f(a.w & 0xffffu), bf2f(b.w & 0xffffu), acc);
    acc = fmaf(bf2f(a.w >> 16),     bf2f(b.w >> 16),     acc);
  }
  acc = dpp_red8(acc);
  if (gl == 0 && dsc.y >= 0) y[dsc.y] = acc;
}

__launch_bounds__(256)
__global__ void edge_dot_m(const int* __restrict__ rowptrF, const int2* __restrict__ csrF,
                           const ushort_t* __restrict__ Em, const ushort_t* __restrict__ Ed,
                           float* __restrict__ y)
{
  const int m = (blockIdx.x * 256 + threadIdx.x) >> 6;   // one wave per m node
  const int lane = threadIdx.x & 63;
  const int g = lane >> 3;     // edge slot within step (8 edges per step)
  const int gl = lane & 7;     // lane within group (same channel split as before)

  uint4 em[4];
  const uint4* EmR = (const uint4*)(Em + (size_t)m * 256);
#pragma unroll
  for (int i = 0; i < 4; ++i) em[i] = EmR[gl + 8 * i];

  const int beg = __builtin_amdgcn_readfirstlane(rowptrF[m]);
  const int end = __builtin_amdgcn_readfirstlane(rowptrF[m + 1]);

  // 2-slot static pipeline, 8 edges per slot (16 in flight)
  int2 d0, d1;
  uint4 b0[4], b1[4];
  edm_load(csrF, Ed, beg,     end, g, gl, d0, b0);
  edm_load(csrF, Ed, beg + 8, end, g, gl, d1, b1);

  for (int i = beg; i < end; i += 16) {
    edm_compute(em, d0, b0, gl, y);
    edm_load(csrF, Ed, i + 16, end, g, gl, d0, b0);
    if (i + 8 < end) edm_compute(em, d1, b1, gl, y);
    edm_load(csrF, Ed, i + 24, end, g, gl, d1, b1);
  }
}

// ---------- launch ----------
extern "C" void kernel_launch(void* const* d_in, const int* in_sizes, int n_in,
                              void* d_out, int out_size, void* d_ws, size_t ws_size,
                              hipStream_t stream)
{
  const float* x_n1  = (const float*)d_in[0];
  const float* x_n2  = (const float*)d_in[1];
  const float* W_in1 = (const float*)d_in[2];
  const float* b_in1 = (const float*)d_in[3];
  const float* W_in2 = (const float*)d_in[4];
  const float* b_in2 = (const float*)d_in[5];
  const float* Wk_n1 = (const float*)d_in[6];
  const float* bk_n1 = (const float*)d_in[7];
  const float* Wq_n1 = (const float*)d_in[8];
  const float* bq_n1 = (const float*)d_in[9];
  const float* Wv_n1 = (const float*)d_in[10];
  const float* bv_n1 = (const float*)d_in[11];
  const float* Wa_n1 = (const float*)d_in[12];
  const float* ba_n1 = (const float*)d_in[13];
  const float* skip_n1 = (const float*)d_in[14];
  const float* Wk_n2 = (const float*)d_in[15];
  const float* bk_n2 = (const float*)d_in[16];
  const float* Wq_n2 = (const float*)d_in[17];
  const float* bq_n2 = (const float*)d_in[18];
  const float* Wv_n2 = (const float*)d_in[19];
  const float* bv_n2 = (const float*)d_in[20];
  const float* Wa_n2 = (const float*)d_in[21];
  const float* ba_n2 = (const float*)d_in[22];
  const float* skip_n2 = (const float*)d_in[23];
  const float* a_rel_12 = (const float*)d_in[24];
  const float* m_rel_12 = (const float*)d_in[25];
  const float* p_rel_12 = (const float*)d_in[26];
  const float* a_rel_21 = (const float*)d_in[27];
  const float* m_rel_21 = (const float*)d_in[28];
  const float* p_rel_21 = (const float*)d_in[29];
  const int*   ei_12 = (const int*)d_in[30];
  const int*   ei_21 = (const int*)d_in[31];
  const int*   edge_index = (const int*)d_in[32];
  float* y = (float*)d_out;

  // ---- workspace carve-up (float units) ----
  const size_t NF = (size_t)PN1 * 128;
  float* ws = (float*)d_ws;
  float* x1   = ws + 0 * NF;
  float* x2   = ws + 1 * NF;
  float* q1   = ws + 2 * NF;
  float* q2   = ws + 3 * NF;
  float* agg1 = ws + 4 * NF;
  float* agg2 = ws + 5 * NF;
  unsigned* kv1 = (unsigned*)(ws + 6 * NF);
  unsigned* kv2 = (unsigned*)(ws + 7 * NF);
  ushort_t* Em  = (ushort_t*)(ws + 8 * NF);
  ushort_t* Ed  = (ushort_t*)(ws + 8 * NF + 1280000);
  unsigned* wb = (unsigned*)(ws + 8 * NF + 2560000);
  unsigned* WkT1 = wb;                     float* bkF1 = (float*)(wb + 16384);
  unsigned* WvT1 = wb + 16640;             float* bvF1 = (float*)(wb + 33024);
  unsigned* WkT2 = wb + 33280;             float* bkF2 = (float*)(wb + 49664);
  unsigned* WvT2 = wb + 49920;             float* bvF2 = (float*)(wb + 66304);
  unsigned* WinT1 = wb + 66560;
  unsigned* WinT2 = wb + 74752;
  unsigned* WqT1  = wb + 82944;
  unsigned* WqT2  = wb + 99328;
  unsigned* WaT1  = wb + 115712;
  unsigned* WaT2  = wb + 132096;
  int* ip = (int*)(wb + 148480);
  int* rowptr12 = ip;                  // 10016
  int* rowptr21 = ip + 10016;
  int* cur12    = ip + 20032;
  int* cur21    = ip + 30048;
  int* deg12    = ip + 40064;          // deg12, deg21, degF contiguous (one zero pass)
  int* deg21    = ip + 50080;
  int* degF     = ip + 60096;
  int* rowptrF  = ip + 70112;
  int* curF     = ip + 80128;
  int* csr12    = ip + 90144;
  int* csr21    = ip + 90144 + NE12;
  int2* csrF    = (int2*)(ip + 90144 + NE12 + NE21);   // int offset 730144 (8B aligned)

  const int EBF = (NEF + 255) / 256;   // 1954 — covers all three edge lists

  // ---- one preprocessing dispatch ----
  prep<<<dim3(33, 19), 256, 0, stream>>>(
      W_in1, W_in2, Wq_n1, Wq_n2, Wa_n1, Wa_n2,
      Wk_n1, bk_n1, Wv_n1, bv_n1, Wk_n2, bk_n2, Wv_n2, bv_n2,
      a_rel_12, m_rel_12, a_rel_21, m_rel_21,
      WinT1, WinT2, WqT1, WqT2, WaT1, WaT2,
      WkT1, bkF1, WvT1, bvF1, WkT2, bkF2, WvT2, bvF2, deg12);

  // ---- CSR build (2 attention graphs + readout m-buckets) ----
  csr_hist3<<<EBF, 256, 0, stream>>>(ei_12 + NE12, ei_21 + NE21, edge_index,
                                     deg12, deg21, degF);
  csr_scan3<<<3, 256, 0, stream>>>(deg12, rowptr12, cur12, PN2, NE12,
                                   deg21, rowptr21, cur21, PN1, NE21,
                                   degF, rowptrF, curF, PN1, NEF);
  csr_scatter3<<<EBF, 256, 0, stream>>>(ei_12, ei_12 + NE12, cur12, csr12,
                                        ei_21, ei_21 + NE21, cur21, csr21,
                                        edge_index, edge_index + NEF, curF, csrF);

  // ---- input projections + relu ----
  mfma_gemm1<<<2 * GB, 256, 0, stream>>>(x_n1, x_n2, WinT1, b_in1, WinT2, b_in2,
                                         x1, x2, GB, PN1, 0,
                                         nullptr, nullptr, nullptr, nullptr, 0);

  for (int l = 0; l < NLAY; ++l) {
    const int bo = l * 128;
    mfma_kvq<<<2 * GB, 256, 0, stream>>>(
        x1, x2,
        WqT1 + (size_t)l * 8192, WkT1 + (size_t)l * 8192, WvT1 + (size_t)l * 8192,
        bq_n1 + bo, bkF1 + bo, bvF1 + bo,
        WqT2 + (size_t)l * 8192, WkT2 + (size_t)l * 8192, WvT2 + (size_t)l * 8192,
        bq_n2 + bo, bkF2 + bo, bvF2 + bo,
        q1, kv1, q2, kv2, GB, PN1);

    attn_gather2<<<(2 * PN1) / 4, 256, 0, stream>>>(
        rowptr12, csr12, q2, kv1, p_rel_12 + l * NH,
        rowptr21, csr21, q1, kv2, p_rel_21 + l * NH,
        agg2, agg1);

    mfma_gemm1<<<2 * GB, 256, 0, stream>>>(
        agg1, agg2, WaT1 + (size_t)l * 8192, ba_n1 + bo,
        WaT2 + (size_t)l * 8192, ba_n2 + bo,
        x1, x2, GB, PN1, 2, skip_n1 + l, skip_n2 + l, Em, Ed, bo);
  }

  // ---- readout: one wave per m-node (10000 waves = 2500 blocks) ----
  edge_dot_m<<<2500, 256, 0, stream>>>(rowptrF, csrF, Em, Ed, y);
}

// Round 14
// 436.118 us; speedup vs baseline: 1.0759x; 1.0759x over previous
//
#include <hip/hip_runtime.h>
#include <cstdint>
#include <cstddef>

typedef unsigned short ushort_t;
typedef __attribute__((ext_vector_type(8))) short bf16x8;
typedef __attribute__((ext_vector_type(4))) float f32x4;

// Problem constants
#define PN1   10000
#define PN2   10000
#define NH    8
#define NLAY  2
#define NE12  320000
#define NE21  320000
#define NEF   500000

// ---------- bf16 helpers (RNE) ----------
__device__ __forceinline__ unsigned f2bf(float f) {
  union { float f; unsigned u; } v; v.f = f;
  return (v.u + 0x7FFFu + ((v.u >> 16) & 1u)) >> 16;
}
__device__ __forceinline__ float bf2f(unsigned s) {
  union { float f; unsigned u; } v; v.u = s << 16; return v.f;
}
union U4 { uint4 u; bf16x8 s; };

// ---------- DPP helpers ----------
__device__ __forceinline__ float dpp_red8(float x) {
  int t;
  t = __builtin_amdgcn_update_dpp(0, __float_as_int(x), 0xB1,  0xf, 0xf, true);
  x += __int_as_float(t);
  t = __builtin_amdgcn_update_dpp(0, __float_as_int(x), 0x4E,  0xf, 0xf, true);
  x += __int_as_float(t);
  t = __builtin_amdgcn_update_dpp(0, __float_as_int(x), 0x141, 0xf, 0xf, true);
  x += __int_as_float(t);
  return x;
}
__device__ __forceinline__ float dpp_red4(float x) {
  int t;
  t = __builtin_amdgcn_update_dpp(0, __float_as_int(x), 0xB1, 0xf, 0xf, true);
  x += __int_as_float(t);
  t = __builtin_amdgcn_update_dpp(0, __float_as_int(x), 0x4E, 0xf, 0xf, true);
  x += __int_as_float(t);
  return x;
}
__device__ __forceinline__ float dpp_xor1(float x) {
  return __int_as_float(__builtin_amdgcn_update_dpp(0, __float_as_int(x), 0xB1, 0xf, 0xf, true));
}

// ============================================================================
// MFMA GEMM core: 4 waves, tile 64x128, K=128.
// ============================================================================
#define GB 157   // ceil(10000/64)

__device__ __forceinline__ void stage_A(const float* __restrict__ X, unsigned* sA,
                                        int rowbase, int N, int tid)
{
#pragma unroll
  for (int i = 0; i < 8; ++i) {
    int idx = tid + i * 256;
    int r = idx >> 5;
    int c4 = (idx & 31) << 2;
    int gr = rowbase + r;
    float4 v = make_float4(0.f, 0.f, 0.f, 0.f);
    if (gr < N) v = *(const float4*)(X + (size_t)gr * 128 + c4);
    sA[r * 68 + (c4 >> 1)]     = f2bf(v.x) | (f2bf(v.y) << 16);
    sA[r * 68 + (c4 >> 1) + 1] = f2bf(v.z) | (f2bf(v.w) << 16);
  }
}

__device__ __forceinline__ void stage_B(const unsigned* __restrict__ Wt, unsigned* sB, int tid)
{
#pragma unroll
  for (int i = 0; i < 8; ++i) {
    int idx = tid + i * 256;
    int n = idx >> 4;
    int k4 = (idx & 15) << 2;
    *(uint4*)&sB[n * 68 + k4] = *(const uint4*)&Wt[(size_t)idx << 2];
  }
}

__device__ __forceinline__ void mfma_compute(const unsigned* sA, const unsigned* sB,
                                             int w, int lane, f32x4 acc[8])
{
#pragma unroll
  for (int ks = 0; ks < 4; ++ks) {
    U4 a; a.u = *(const uint4*)&sA[(w * 16 + (lane & 15)) * 68 + ks * 16 + ((lane >> 4) << 2)];
#pragma unroll
    for (int t = 0; t < 8; ++t) {
      U4 b; b.u = *(const uint4*)&sB[(t * 16 + (lane & 15)) * 68 + ks * 16 + ((lane >> 4) << 2)];
      acc[t] = __builtin_amdgcn_mfma_f32_16x16x32_bf16(a.s, b.s, acc[t], 0, 0, 0);
    }
  }
}

// ---------- single-matrix GEMM: mode 0 = relu; mode 2 = skip-blend + cat ----------
__launch_bounds__(256, 2)
__global__ void mfma_gemm1(const float* __restrict__ X1, const float* __restrict__ X2,
                           const unsigned* __restrict__ W1t, const float* __restrict__ b1,
                           const unsigned* __restrict__ W2t, const float* __restrict__ b2,
                           float* __restrict__ Y1, float* __restrict__ Y2,
                           int nb1, int N, int mode,
                           const float* __restrict__ skip1, const float* __restrict__ skip2,
                           ushort_t* __restrict__ cat1, ushort_t* __restrict__ cat2, int catoff)
{
  __shared__ unsigned sA[64 * 68];
  __shared__ unsigned sB[128 * 68];
  const int tid = threadIdx.x;
  const bool t2 = blockIdx.x >= nb1;
  const int rowbase = (t2 ? blockIdx.x - nb1 : blockIdx.x) * 64;
  const float* X = t2 ? X2 : X1;
  const unsigned* Wt = t2 ? W2t : W1t;
  const float* bias = t2 ? b2 : b1;
  float* Y = t2 ? Y2 : Y1;
  ushort_t* cat = t2 ? cat2 : cat1;

  stage_A(X, sA, rowbase, N, tid);
  stage_B(Wt, sB, tid);
  __syncthreads();

  const int w = tid >> 6, lane = tid & 63;
  f32x4 acc[8];
#pragma unroll
  for (int t = 0; t < 8; ++t) acc[t] = (f32x4){0.f, 0.f, 0.f, 0.f};
  mfma_compute(sA, sB, w, lane, acc);

  float beta = 0.f;
  if (mode == 2) beta = 1.0f / (1.0f + expf(-((t2 ? skip2 : skip1)[0])));
  const int cb = lane & 15;
  const int rq = (lane >> 4) << 2;
#pragma unroll
  for (int t = 0; t < 8; ++t) {
    int c = t * 16 + cb;
    float bv = bias[c];
#pragma unroll
    for (int r = 0; r < 4; ++r) {
      int row = rowbase + w * 16 + rq + r;
      float val = acc[t][r] + bv;
      if (mode == 0) {
        if (row < N) Y[(size_t)row * 128 + c] = fmaxf(val, 0.f);
      } else {
        float xo = (row < N) ? Y[(size_t)row * 128 + c] : 0.f;
        float tv = beta * val + (1.f - beta) * xo;
        if (row < N) Y[(size_t)row * 128 + c] = tv;
        float nb = dpp_xor1(tv);
        if (((lane & 1) == 0) && row < N)
          *(unsigned*)(cat + (size_t)row * 256 + catoff + c) = f2bf(tv) | (f2bf(nb) << 16);
      }
    }
  }
}

// ---------- fused K/V/Q projection (3 matrices, shared A) ----------
__launch_bounds__(256, 2)
__global__ void mfma_kvq(const float* __restrict__ X1, const float* __restrict__ X2,
                         const unsigned* __restrict__ WqT1, const unsigned* __restrict__ WkT1,
                         const unsigned* __restrict__ WvT1,
                         const float* __restrict__ bq1, const float* __restrict__ bk1,
                         const float* __restrict__ bv1,
                         const unsigned* __restrict__ WqT2, const unsigned* __restrict__ WkT2,
                         const unsigned* __restrict__ WvT2,
                         const float* __restrict__ bq2, const float* __restrict__ bk2,
                         const float* __restrict__ bv2,
                         float* __restrict__ q1o, unsigned* __restrict__ kv1,
                         float* __restrict__ q2o, unsigned* __restrict__ kv2,
                         int nb1, int N)
{
  __shared__ unsigned sA[64 * 68];
  __shared__ unsigned sB[128 * 68];
  const int tid = threadIdx.x;
  const bool t2 = blockIdx.x >= nb1;
  const int rowbase = (t2 ? blockIdx.x - nb1 : blockIdx.x) * 64;
  const float* X = t2 ? X2 : X1;
  const unsigned* Wt[3] = { t2 ? WqT2 : WqT1, t2 ? WkT2 : WkT1, t2 ? WvT2 : WvT1 };
  const float* bs[3] = { t2 ? bq2 : bq1, t2 ? bk2 : bk1, t2 ? bv2 : bv1 };
  float* qo = t2 ? q2o : q1o;
  unsigned* kvo = t2 ? kv2 : kv1;

  stage_A(X, sA, rowbase, N, tid);
  const int w = tid >> 6, lane = tid & 63;
  const int cb = lane & 15;
  const int rq = (lane >> 4) << 2;

  for (int j = 0; j < 3; ++j) {
    if (j > 0) __syncthreads();
    stage_B(Wt[j], sB, tid);
    __syncthreads();
    f32x4 acc[8];
#pragma unroll
    for (int t = 0; t < 8; ++t) acc[t] = (f32x4){0.f, 0.f, 0.f, 0.f};
    mfma_compute(sA, sB, w, lane, acc);

#pragma unroll
    for (int t = 0; t < 8; ++t) {
      int c = t * 16 + cb;
      float bv = bs[j][c];
#pragma unroll
      for (int r = 0; r < 4; ++r) {
        int row = rowbase + w * 16 + rq + r;
        float val = acc[t][r] + bv;
        if (j == 0) {
          if (row < N) qo[(size_t)row * 128 + c] = val;
        } else {
          float nb = dpp_xor1(val);
          if (((lane & 1) == 0) && row < N) {
            unsigned pk = f2bf(val) | (f2bf(nb) << 16);
            kvo[(size_t)row * 128 + c + (j == 1 ? 0 : 1)] = pk;
          }
        }
      }
    }
  }
}

// ---------- ONE preprocessing kernel ----------
__global__ void prep(const float* W_in1, const float* W_in2,
                     const float* Wq_n1, const float* Wq_n2,
                     const float* Wa_n1, const float* Wa_n2,
                     const float* Wk_n1, const float* bk_n1,
                     const float* Wv_n1, const float* bv_n1,
                     const float* Wk_n2, const float* bk_n2,
                     const float* Wv_n2, const float* bv_n2,
                     const float* a_rel_12, const float* m_rel_12,
                     const float* a_rel_21, const float* m_rel_21,
                     unsigned* WinT1, unsigned* WinT2,
                     unsigned* WqT1, unsigned* WqT2,
                     unsigned* WaT1, unsigned* WaT2,
                     unsigned* WkT1, float* bkF1, unsigned* WvT1, float* bvF1,
                     unsigned* WkT2, float* bkF2, unsigned* WvT2, float* bvF2,
                     int* deg)
{
  const int yid = blockIdx.y;
  int idx = blockIdx.x * 256 + threadIdx.x;

  if (yid < 10) {
    if (idx >= 8192) return;
    const float* W; unsigned* Wt;
    switch (yid) {
      case 0: W = W_in1;          Wt = WinT1;        break;
      case 1: W = W_in2;          Wt = WinT2;        break;
      case 2: W = Wq_n1;          Wt = WqT1;         break;
      case 3: W = Wq_n1 + 16384;  Wt = WqT1 + 8192;  break;
      case 4: W = Wq_n2;          Wt = WqT2;         break;
      case 5: W = Wq_n2 + 16384;  Wt = WqT2 + 8192;  break;
      case 6: W = Wa_n1;          Wt = WaT1;         break;
      case 7: W = Wa_n1 + 16384;  Wt = WaT1 + 8192;  break;
      case 8: W = Wa_n2;          Wt = WaT2;         break;
      default: W = Wa_n2 + 16384; Wt = WaT2 + 8192;  break;
    }
    int n = idx & 127, kp = idx >> 7;
    float a = W[(size_t)(2 * kp) * 128 + n];
    float b = W[(size_t)(2 * kp + 1) * 128 + n];
    Wt[n * 64 + kp] = f2bf(a) | (f2bf(b) << 16);
  } else if (yid < 18) {
    int job = yid - 10;
    int l = job >> 2, m = job & 3;
    const float *W, *b, *rel; unsigned* Wt; float* bf;
    switch (m) {
      case 0:  W = Wk_n1; b = bk_n1; rel = a_rel_12; Wt = WkT1; bf = bkF1; break;
      case 1:  W = Wv_n1; b = bv_n1; rel = m_rel_12; Wt = WvT1; bf = bvF1; break;
      case 2:  W = Wk_n2; b = bk_n2; rel = a_rel_21; Wt = WkT2; bf = bkF2; break;
      default: W = Wv_n2; b = bv_n2; rel = m_rel_21; Wt = WvT2; bf = bvF2; break;
    }
    W += (size_t)l * 16384; b += l * 128; rel += (size_t)l * 2048;
    Wt += (size_t)l * 8192; bf += l * 128;
    if (idx < 8192) {
      int n = idx & 127, kp = idx >> 7;
      int h = n >> 4, e = n & 15;
      const float* rr = rel + h * 256;
      const float* s0 = W + (size_t)(2 * kp) * 128 + h * 16;
      const float* s1 = s0 + 128;
      float a0 = 0.f, a1 = 0.f;
#pragma unroll
      for (int d = 0; d < 16; ++d) {
        float rv = rr[d * 16 + e];
        a0 = fmaf(s0[d], rv, a0);
        a1 = fmaf(s1[d], rv, a1);
      }
      Wt[n * 64 + kp] = f2bf(a0) | (f2bf(a1) << 16);
    } else if (idx < 8320) {
      int n = idx - 8192;
      int h = n >> 4, e = n & 15;
      const float* rr = rel + h * 256;
      float a = 0.f;
#pragma unroll
      for (int d = 0; d < 16; ++d) a = fmaf(b[h * 16 + d], rr[d * 16 + e], a);
      bf[n] = a;
    }
  } else {
    for (int k = idx; k < 20032; k += 8448) deg[k] = 0;
  }
}

// ---------- CSR build (both graphs) ----------
__global__ void csr_hist2(const int* __restrict__ dst12, const int* __restrict__ dst21,
                          int* __restrict__ deg12, int* __restrict__ deg21)
{
  int e = blockIdx.x * 256 + threadIdx.x;
  if (e < NE12) atomicAdd(&deg12[dst12[e]], 1);
  if (e < NE21) atomicAdd(&deg21[dst21[e]], 1);
}

__global__ void csr_scan2(const int* __restrict__ degA, int* __restrict__ rowptrA,
                          int* __restrict__ cursorA, int NA, int EA,
                          const int* __restrict__ degB, int* __restrict__ rowptrB,
                          int* __restrict__ cursorB, int NB, int EB)
{
  const int* deg = blockIdx.x ? degB : degA;
  int* rowptr = blockIdx.x ? rowptrB : rowptrA;
  int* cursor = blockIdx.x ? cursorB : cursorA;
  const int N = blockIdx.x ? NB : NA;
  const int E = blockIdx.x ? EB : EA;
  __shared__ int part[256];
  const int t = threadIdx.x;
  const int chunk = (N + 255) / 256;
  const int b = t * chunk;
  const int e = (b + chunk < N) ? b + chunk : N;
  int s = 0;
  for (int i = b; i < e; ++i) s += deg[i];
  part[t] = s;
  __syncthreads();
  if (t == 0) {
    int run = 0;
    for (int i = 0; i < 256; ++i) { int v = part[i]; part[i] = run; run += v; }
  }
  __syncthreads();
  int run = part[t];
  for (int i = b; i < e; ++i) { rowptr[i] = run; cursor[i] = run; run += deg[i]; }
  if (t == 0) rowptr[N] = E;
}

__global__ void csr_scatter2(const int* __restrict__ src12, const int* __restrict__ dst12,
                             int* __restrict__ cur12, int* __restrict__ csr12,
                             const int* __restrict__ src21, const int* __restrict__ dst21,
                             int* __restrict__ cur21, int* __restrict__ csr21)
{
  int e = blockIdx.x * 256 + threadIdx.x;
  if (e < NE12) {
    int p = atomicAdd(&cur12[dst12[e]], 1);
    __builtin_nontemporal_store(src12[e], &csr12[p]);   // streaming: reduce partial-line writeback
  }
  if (e < NE21) {
    int p = atomicAdd(&cur21[dst21[e]], 1);
    __builtin_nontemporal_store(src21[e], &csr21[p]);
  }
}

// ---------- fused gather attention (R12's wide-load, static-index version) ----------
__launch_bounds__(256)
__global__ void attn_gather2(const int* __restrict__ rowptr12, const int* __restrict__ csr12,
                             const float* __restrict__ q2, const unsigned* __restrict__ kv1,
                             const float* __restrict__ pr12,
                             const int* __restrict__ rowptr21, const int* __restrict__ csr21,
                             const float* __restrict__ q1, const unsigned* __restrict__ kv2,
                             const float* __restrict__ pr21,
                             float* __restrict__ agg2, float* __restrict__ agg1)
{
  const int wid = (blockIdx.x * 256 + threadIdx.x) >> 6;
  const int lane = threadIdx.x & 63;
  const int sub = lane >> 5;
  const int sl = lane & 31;
  const bool dirB = wid >= PN2;
  const int d = __builtin_amdgcn_readfirstlane(dirB ? wid - PN2 : wid);
  const int* rowptr = dirB ? rowptr21 : rowptr12;
  const int* csr    = dirB ? csr21 : csr12;
  const float* q    = dirB ? q1 : q2;
  const unsigned* kv = dirB ? kv2 : kv1;
  const float* prel = dirB ? pr21 : pr12;
  float* agg = dirB ? agg1 : agg2;

  const int h = sl >> 2;
  const float4 qv = *(const float4*)(q + (size_t)d * 128 + 4 * sl);
  const float pr2 = prel[h] * (0.25f * 1.4426950408889634f);
  const int beg = __builtin_amdgcn_readfirstlane(rowptr[d]);
  const int end = __builtin_amdgcn_readfirstlane(rowptr[d + 1]);
  const int co = 4 * sl;

  float ssum = 0.f, a0 = 0.f, a1 = 0.f, a2 = 0.f, a3 = 0.f;

  uint4 buf[4];
#pragma unroll
  for (int j = 0; j < 4; ++j) {
    int idx = beg + 2 * j + sub;
    int s = (idx < end) ? csr[idx] : 0;
    buf[j] = *(const uint4*)(kv + (size_t)s * 128 + co);
  }

  for (int i = beg; i < end; i += 8) {
    uint4 cur[4];
#pragma unroll
    for (int j = 0; j < 4; ++j) cur[j] = buf[j];
#pragma unroll
    for (int j = 0; j < 4; ++j) {
      int idx = i + 8 + 2 * j + sub;
      int s = (idx < end) ? csr[idx] : 0;
      buf[j] = *(const uint4*)(kv + (size_t)s * 128 + co);
    }
    float p[4], ex[4];
#pragma unroll
    for (int j = 0; j < 4; ++j) {
      float t = qv.x * bf2f(cur[j].x & 0xffffu);
      t = fmaf(qv.y, bf2f(cur[j].x >> 16), t);
      t = fmaf(qv.z, bf2f(cur[j].z & 0xffffu), t);
      p[j] = fmaf(qv.w, bf2f(cur[j].z >> 16), t);
    }
#pragma unroll
    for (int j = 0; j < 4; ++j) p[j] = dpp_red4(p[j]);
#pragma unroll
    for (int j = 0; j < 4; ++j)
      ex[j] = (i + 2 * j + sub < end) ? exp2f(p[j] * pr2) : 0.f;
    ssum += (ex[0] + ex[1]) + (ex[2] + ex[3]);
#pragma unroll
    for (int j = 0; j < 4; ++j) {
      a0 = fmaf(ex[j], bf2f(cur[j].y & 0xffffu), a0);
      a1 = fmaf(ex[j], bf2f(cur[j].y >> 16),     a1);
      a2 = fmaf(ex[j], bf2f(cur[j].w & 0xffffu), a2);
      a3 = fmaf(ex[j], bf2f(cur[j].w >> 16),     a3);
    }
  }

  ssum += __shfl_xor(ssum, 32);
  a0 += __shfl_xor(a0, 32);
  a1 += __shfl_xor(a1, 32);
  a2 += __shfl_xor(a2, 32);
  a3 += __shfl_xor(a3, 32);

  if (sub == 0) {
    const float inv = 1.0f / (ssum + 1e-16f);
    float o0 = a0 * inv, o1 = a1 * inv, o2 = a2 * inv, o3 = a3 * inv;
    o0 = 0.5f * o0 * (1.f + erff(o0 * 0.70710678118654752f));
    o1 = 0.5f * o1 * (1.f + erff(o1 * 0.70710678118654752f));
    o2 = 0.5f * o2 * (1.f + erff(o2 * 0.70710678118654752f));
    o3 = 0.5f * o3 * (1.f + erff(o3 * 0.70710678118654752f));
    float4 out; out.x = o0; out.y = o1; out.z = o2; out.w = o3;
    *(float4*)(agg + (size_t)d * 128 + co) = out;
  }
}

// ---------- readout: 2 edges per 8-lane group, all 16 loads in flight ----------
// Per-edge fp32 fma order is bit-identical to R12's edge_dot_bf.
__launch_bounds__(256)
__global__ void edge_dot_bf(const int* __restrict__ mi, const int* __restrict__ di,
                            const ushort_t* __restrict__ Em, const ushort_t* __restrict__ Ed,
                            float* __restrict__ y, int E)
{
  int t = blockIdx.x * 256 + threadIdx.x;
  int g = t >> 3;
  int gl = t & 7;
  int e0 = 2 * g;
  if (e0 >= E) return;
  const bool has1 = (e0 + 1 < E);
  int m0 = mi[e0], d0 = di[e0];
  int m1 = has1 ? mi[e0 + 1] : m0;
  int d1 = has1 ? di[e0 + 1] : d0;
  const uint4* A0 = (const uint4*)(Em + (size_t)m0 * 256);
  const uint4* B0 = (const uint4*)(Ed + (size_t)d0 * 256);
  const uint4* A1 = (const uint4*)(Em + (size_t)m1 * 256);
  const uint4* B1 = (const uint4*)(Ed + (size_t)d1 * 256);

  uint4 a0[4], b0[4], a1[4], b1[4];
#pragma unroll
  for (int i = 0; i < 4; ++i) { a0[i] = A0[gl + 8 * i]; b0[i] = B0[gl + 8 * i]; }
#pragma unroll
  for (int i = 0; i < 4; ++i) { a1[i] = A1[gl + 8 * i]; b1[i] = B1[gl + 8 * i]; }

  float acc0 = 0.f, acc1 = 0.f;
#pragma unroll
  for (int i = 0; i < 4; ++i) {
    uint4 a = a0[i], b = b0[i];
    acc0 = fmaf(bf2f(a.x & 0xffffu), bf2f(b.x & 0xffffu), acc0);
    acc0 = fmaf(bf2f(a.x >> 16),     bf2f(b.x >> 16),     acc0);
    acc0 = fmaf(bf2f(a.y & 0xffffu), bf2f(b.y & 0xffffu), acc0);
    acc0 = fmaf(bf2f(a.y >> 16),     bf2f(b.y >> 16),     acc0);
    acc0 = fmaf(bf2f(a.z & 0xffffu), bf2f(b.z & 0xffffu), acc0);
    acc0 = fmaf(bf2f(a.z >> 16),     bf2f(b.z >> 16),     acc0);
    acc0 = fmaf(bf2f(a.w & 0xffffu), bf2f(b.w & 0xffffu), acc0);
    acc0 = fmaf(bf2f(a.w >> 16),     bf2f(b.w >> 16),     acc0);
  }
#pragma unroll
  for (int i = 0; i < 4; ++i) {
    uint4 a = a1[i], b = b1[i];
    acc1 = fmaf(bf2f(a.x & 0xffffu), bf2f(b.x & 0xffffu), acc1);
    acc1 = fmaf(bf2f(a.x >> 16),     bf2f(b.x >> 16),     acc1);
    acc1 = fmaf(bf2f(a.y & 0xffffu), bf2f(b.y & 0xffffu), acc1);
    acc1 = fmaf(bf2f(a.y >> 16),     bf2f(b.y >> 16),     acc1);
    acc1 = fmaf(bf2f(a.z & 0xffffu), bf2f(b.z & 0xffffu), acc1);
    acc1 = fmaf(bf2f(a.z >> 16),     bf2f(b.z >> 16),     acc1);
    acc1 = fmaf(bf2f(a.w & 0xffffu), bf2f(b.w & 0xffffu), acc1);
    acc1 = fmaf(bf2f(a.w >> 16),     bf2f(b.w >> 16),     acc1);
  }
  acc0 = dpp_red8(acc0);
  acc1 = dpp_red8(acc1);
  if (gl == 0) {
    y[e0] = acc0;
    if (has1) y[e0 + 1] = acc1;
  }
}

// ---------- launch ----------
extern "C" void kernel_launch(void* const* d_in, const int* in_sizes, int n_in,
                              void* d_out, int out_size, void* d_ws, size_t ws_size,
                              hipStream_t stream)
{
  const float* x_n1  = (const float*)d_in[0];
  const float* x_n2  = (const float*)d_in[1];
  const float* W_in1 = (const float*)d_in[2];
  const float* b_in1 = (const float*)d_in[3];
  const float* W_in2 = (const float*)d_in[4];
  const float* b_in2 = (const float*)d_in[5];
  const float* Wk_n1 = (const float*)d_in[6];
  const float* bk_n1 = (const float*)d_in[7];
  const float* Wq_n1 = (const float*)d_in[8];
  const float* bq_n1 = (const float*)d_in[9];
  const float* Wv_n1 = (const float*)d_in[10];
  const float* bv_n1 = (const float*)d_in[11];
  const float* Wa_n1 = (const float*)d_in[12];
  const float* ba_n1 = (const float*)d_in[13];
  const float* skip_n1 = (const float*)d_in[14];
  const float* Wk_n2 = (const float*)d_in[15];
  const float* bk_n2 = (const float*)d_in[16];
  const float* Wq_n2 = (const float*)d_in[17];
  const float* bq_n2 = (const float*)d_in[18];
  const float* Wv_n2 = (const float*)d_in[19];
  const float* bv_n2 = (const float*)d_in[20];
  const float* Wa_n2 = (const float*)d_in[21];
  const float* ba_n2 = (const float*)d_in[22];
  const float* skip_n2 = (const float*)d_in[23];
  const float* a_rel_12 = (const float*)d_in[24];
  const float* m_rel_12 = (const float*)d_in[25];
  const float* p_rel_12 = (const float*)d_in[26];
  const float* a_rel_21 = (const float*)d_in[27];
  const float* m_rel_21 = (const float*)d_in[28];
  const float* p_rel_21 = (const float*)d_in[29];
  const int*   ei_12 = (const int*)d_in[30];
  const int*   ei_21 = (const int*)d_in[31];
  const int*   edge_index = (const int*)d_in[32];
  float* y = (float*)d_out;

  // ---- workspace carve-up (float units) ----
  const size_t NF = (size_t)PN1 * 128;
  float* ws = (float*)d_ws;
  float* x1   = ws + 0 * NF;
  float* x2   = ws + 1 * NF;
  float* q1   = ws + 2 * NF;
  float* q2   = ws + 3 * NF;
  float* agg1 = ws + 4 * NF;
  float* agg2 = ws + 5 * NF;
  unsigned* kv1 = (unsigned*)(ws + 6 * NF);
  unsigned* kv2 = (unsigned*)(ws + 7 * NF);
  ushort_t* Em  = (ushort_t*)(ws + 8 * NF);
  ushort_t* Ed  = (ushort_t*)(ws + 8 * NF + 1280000);
  unsigned* wb = (unsigned*)(ws + 8 * NF + 2560000);
  unsigned* WkT1 = wb;                     float* bkF1 = (float*)(wb + 16384);
  unsigned* WvT1 = wb + 16640;             float* bvF1 = (float*)(wb + 33024);
  unsigned* WkT2 = wb + 33280;             float* bkF2 = (float*)(wb + 49664);
  unsigned* WvT2 = wb + 49920;             float* bvF2 = (float*)(wb + 66304);
  unsigned* WinT1 = wb + 66560;
  unsigned* WinT2 = wb + 74752;
  unsigned* WqT1  = wb + 82944;
  unsigned* WqT2  = wb + 99328;
  unsigned* WaT1  = wb + 115712;
  unsigned* WaT2  = wb + 132096;
  int* ip = (int*)(wb + 148480);
  int* rowptr12 = ip;
  int* rowptr21 = ip + 10016;
  int* cur12    = ip + 20032;
  int* cur21    = ip + 30048;
  int* deg12    = ip + 40064;
  int* deg21    = ip + 50080;
  int* csr12    = ip + 60096;
  int* csr21    = ip + 60096 + NE12;

  const int EB = (NE12 + 255) / 256;

  // ---- one preprocessing dispatch ----
  prep<<<dim3(33, 19), 256, 0, stream>>>(
      W_in1, W_in2, Wq_n1, Wq_n2, Wa_n1, Wa_n2,
      Wk_n1, bk_n1, Wv_n1, bv_n1, Wk_n2, bk_n2, Wv_n2, bv_n2,
      a_rel_12, m_rel_12, a_rel_21, m_rel_21,
      WinT1, WinT2, WqT1, WqT2, WaT1, WaT2,
      WkT1, bkF1, WvT1, bvF1, WkT2, bkF2, WvT2, bvF2, deg12);

  // ---- CSR build ----
  csr_hist2<<<EB, 256, 0, stream>>>(ei_12 + NE12, ei_21 + NE21, deg12, deg21);
  csr_scan2<<<2, 256, 0, stream>>>(deg12, rowptr12, cur12, PN2, NE12,
                                   deg21, rowptr21, cur21, PN1, NE21);
  csr_scatter2<<<EB, 256, 0, stream>>>(ei_12, ei_12 + NE12, cur12, csr12,
                                       ei_21, ei_21 + NE21, cur21, csr21);

  // ---- input projections + relu ----
  mfma_gemm1<<<2 * GB, 256, 0, stream>>>(x_n1, x_n2, WinT1, b_in1, WinT2, b_in2,
                                         x1, x2, GB, PN1, 0,
                                         nullptr, nullptr, nullptr, nullptr, 0);

  for (int l = 0; l < NLAY; ++l) {
    const int bo = l * 128;
    mfma_kvq<<<2 * GB, 256, 0, stream>>>(
        x1, x2,
        WqT1 + (size_t)l * 8192, WkT1 + (size_t)l * 8192, WvT1 + (size_t)l * 8192,
        bq_n1 + bo, bkF1 + bo, bvF1 + bo,
        WqT2 + (size_t)l * 8192, WkT2 + (size_t)l * 8192, WvT2 + (size_t)l * 8192,
        bq_n2 + bo, bkF2 + bo, bvF2 + bo,
        q1, kv1, q2, kv2, GB, PN1);

    attn_gather2<<<(2 * PN1) / 4, 256, 0, stream>>>(
        rowptr12, csr12, q2, kv1, p_rel_12 + l * NH,
        rowptr21, csr21, q1, kv2, p_rel_21 + l * NH,
        agg2, agg1);

    mfma_gemm1<<<2 * GB, 256, 0, stream>>>(
        agg1, agg2, WaT1 + (size_t)l * 8192, ba_n1 + bo,
        WaT2 + (size_t)l * 8192, ba_n2 + bo,
        x1, x2, GB, PN1, 2, skip_n1 + l, skip_n2 + l, Em, Ed, bo);
  }

  // ---- readout: 2 edges per 8-lane group ----
  const int DOT_B = (((NEF + 1) / 2) * 8 + 255) / 256;   // 7813
  edge_dot_bf<<<DOT_B, 256, 0, stream>>>(edge_index, edge_index + NEF, Em, Ed, y, NEF);
}

// Round 15
// 429.864 us; speedup vs baseline: 1.0915x; 1.0145x over previous
//
#include <hip/hip_runtime.h>
#include <cstdint>
#include <cstddef>

typedef unsigned short ushort_t;
typedef __attribute__((ext_vector_type(8))) short bf16x8;
typedef __attribute__((ext_vector_type(4))) float f32x4;

// Problem constants
#define PN1   10000
#define PN2   10000
#define NH    8
#define NLAY  2
#define NE12  320000
#define NE21  320000
#define NEF   500000

// ---------- bf16 helpers (RNE) ----------
__device__ __forceinline__ unsigned f2bf(float f) {
  union { float f; unsigned u; } v; v.f = f;
  return (v.u + 0x7FFFu + ((v.u >> 16) & 1u)) >> 16;
}
__device__ __forceinline__ float bf2f(unsigned s) {
  union { float f; unsigned u; } v; v.u = s << 16; return v.f;
}
union U4 { uint4 u; bf16x8 s; };

// ---------- DPP helpers ----------
__device__ __forceinline__ float dpp_red8(float x) {
  int t;
  t = __builtin_amdgcn_update_dpp(0, __float_as_int(x), 0xB1,  0xf, 0xf, true);
  x += __int_as_float(t);
  t = __builtin_amdgcn_update_dpp(0, __float_as_int(x), 0x4E,  0xf, 0xf, true);
  x += __int_as_float(t);
  t = __builtin_amdgcn_update_dpp(0, __float_as_int(x), 0x141, 0xf, 0xf, true);
  x += __int_as_float(t);
  return x;
}
__device__ __forceinline__ float dpp_red4(float x) {
  int t;
  t = __builtin_amdgcn_update_dpp(0, __float_as_int(x), 0xB1, 0xf, 0xf, true);
  x += __int_as_float(t);
  t = __builtin_amdgcn_update_dpp(0, __float_as_int(x), 0x4E, 0xf, 0xf, true);
  x += __int_as_float(t);
  return x;
}
__device__ __forceinline__ float dpp_xor1(float x) {
  return __int_as_float(__builtin_amdgcn_update_dpp(0, __float_as_int(x), 0xB1, 0xf, 0xf, true));
}

// ============================================================================
// MFMA GEMM core: 4 waves, tile 64x128, K=128.
// ============================================================================
#define GB 157   // ceil(10000/64)

__device__ __forceinline__ void stage_A(const float* __restrict__ X, unsigned* sA,
                                        int rowbase, int N, int tid)
{
#pragma unroll
  for (int i = 0; i < 8; ++i) {
    int idx = tid + i * 256;
    int r = idx >> 5;
    int c4 = (idx & 31) << 2;
    int gr = rowbase + r;
    float4 v = make_float4(0.f, 0.f, 0.f, 0.f);
    if (gr < N) v = *(const float4*)(X + (size_t)gr * 128 + c4);
    sA[r * 68 + (c4 >> 1)]     = f2bf(v.x) | (f2bf(v.y) << 16);
    sA[r * 68 + (c4 >> 1) + 1] = f2bf(v.z) | (f2bf(v.w) << 16);
  }
}

__device__ __forceinline__ void stage_B(const unsigned* __restrict__ Wt, unsigned* sB, int tid)
{
#pragma unroll
  for (int i = 0; i < 8; ++i) {
    int idx = tid + i * 256;
    int n = idx >> 4;
    int k4 = (idx & 15) << 2;
    *(uint4*)&sB[n * 68 + k4] = *(const uint4*)&Wt[(size_t)idx << 2];
  }
}

__device__ __forceinline__ void mfma_compute(const unsigned* sA, const unsigned* sB,
                                             int w, int lane, f32x4 acc[8])
{
#pragma unroll
  for (int ks = 0; ks < 4; ++ks) {
    U4 a; a.u = *(const uint4*)&sA[(w * 16 + (lane & 15)) * 68 + ks * 16 + ((lane >> 4) << 2)];
#pragma unroll
    for (int t = 0; t < 8; ++t) {
      U4 b; b.u = *(const uint4*)&sB[(t * 16 + (lane & 15)) * 68 + ks * 16 + ((lane >> 4) << 2)];
      acc[t] = __builtin_amdgcn_mfma_f32_16x16x32_bf16(a.s, b.s, acc[t], 0, 0, 0);
    }
  }
}

// ---------- single-matrix GEMM: mode 0 = relu; mode 2 = skip-blend + cat ----------
__launch_bounds__(256, 2)
__global__ void mfma_gemm1(const float* __restrict__ X1, const float* __restrict__ X2,
                           const unsigned* __restrict__ W1t, const float* __restrict__ b1,
                           const unsigned* __restrict__ W2t, const float* __restrict__ b2,
                           float* __restrict__ Y1, float* __restrict__ Y2,
                           int nb1, int N, int mode,
                           const float* __restrict__ skip1, const float* __restrict__ skip2,
                           ushort_t* __restrict__ cat1, ushort_t* __restrict__ cat2, int catoff)
{
  __shared__ unsigned sA[64 * 68];
  __shared__ unsigned sB[128 * 68];
  const int tid = threadIdx.x;
  const bool t2 = blockIdx.x >= nb1;
  const int rowbase = (t2 ? blockIdx.x - nb1 : blockIdx.x) * 64;
  const float* X = t2 ? X2 : X1;
  const unsigned* Wt = t2 ? W2t : W1t;
  const float* bias = t2 ? b2 : b1;
  float* Y = t2 ? Y2 : Y1;
  ushort_t* cat = t2 ? cat2 : cat1;

  stage_A(X, sA, rowbase, N, tid);
  stage_B(Wt, sB, tid);
  __syncthreads();

  const int w = tid >> 6, lane = tid & 63;
  f32x4 acc[8];
#pragma unroll
  for (int t = 0; t < 8; ++t) acc[t] = (f32x4){0.f, 0.f, 0.f, 0.f};
  mfma_compute(sA, sB, w, lane, acc);

  float beta = 0.f;
  if (mode == 2) beta = 1.0f / (1.0f + expf(-((t2 ? skip2 : skip1)[0])));
  const int cb = lane & 15;
  const int rq = (lane >> 4) << 2;
#pragma unroll
  for (int t = 0; t < 8; ++t) {
    int c = t * 16 + cb;
    float bv = bias[c];
#pragma unroll
    for (int r = 0; r < 4; ++r) {
      int row = rowbase + w * 16 + rq + r;
      float val = acc[t][r] + bv;
      if (mode == 0) {
        if (row < N) Y[(size_t)row * 128 + c] = fmaxf(val, 0.f);
      } else {
        float xo = (row < N) ? Y[(size_t)row * 128 + c] : 0.f;
        float tv = beta * val + (1.f - beta) * xo;
        if (row < N) Y[(size_t)row * 128 + c] = tv;
        float nb = dpp_xor1(tv);
        if (((lane & 1) == 0) && row < N)
          *(unsigned*)(cat + (size_t)row * 256 + catoff + c) = f2bf(tv) | (f2bf(nb) << 16);
      }
    }
  }
}

// ---------- fused K/V/Q projection (3 matrices, shared A) ----------
__launch_bounds__(256, 2)
__global__ void mfma_kvq(const float* __restrict__ X1, const float* __restrict__ X2,
                         const unsigned* __restrict__ WqT1, const unsigned* __restrict__ WkT1,
                         const unsigned* __restrict__ WvT1,
                         const float* __restrict__ bq1, const float* __restrict__ bk1,
                         const float* __restrict__ bv1,
                         const unsigned* __restrict__ WqT2, const unsigned* __restrict__ WkT2,
                         const unsigned* __restrict__ WvT2,
                         const float* __restrict__ bq2, const float* __restrict__ bk2,
                         const float* __restrict__ bv2,
                         float* __restrict__ q1o, unsigned* __restrict__ kv1,
                         float* __restrict__ q2o, unsigned* __restrict__ kv2,
                         int nb1, int N)
{
  __shared__ unsigned sA[64 * 68];
  __shared__ unsigned sB[128 * 68];
  const int tid = threadIdx.x;
  const bool t2 = blockIdx.x >= nb1;
  const int rowbase = (t2 ? blockIdx.x - nb1 : blockIdx.x) * 64;
  const float* X = t2 ? X2 : X1;
  const unsigned* Wt[3] = { t2 ? WqT2 : WqT1, t2 ? WkT2 : WkT1, t2 ? WvT2 : WvT1 };
  const float* bs[3] = { t2 ? bq2 : bq1, t2 ? bk2 : bk1, t2 ? bv2 : bv1 };
  float* qo = t2 ? q2o : q1o;
  unsigned* kvo = t2 ? kv2 : kv1;

  stage_A(X, sA, rowbase, N, tid);
  const int w = tid >> 6, lane = tid & 63;
  const int cb = lane & 15;
  const int rq = (lane >> 4) << 2;

  for (int j = 0; j < 3; ++j) {
    if (j > 0) __syncthreads();
    stage_B(Wt[j], sB, tid);
    __syncthreads();
    f32x4 acc[8];
#pragma unroll
    for (int t = 0; t < 8; ++t) acc[t] = (f32x4){0.f, 0.f, 0.f, 0.f};
    mfma_compute(sA, sB, w, lane, acc);

#pragma unroll
    for (int t = 0; t < 8; ++t) {
      int c = t * 16 + cb;
      float bv = bs[j][c];
#pragma unroll
      for (int r = 0; r < 4; ++r) {
        int row = rowbase + w * 16 + rq + r;
        float val = acc[t][r] + bv;
        if (j == 0) {
          if (row < N) qo[(size_t)row * 128 + c] = val;
        } else {
          float nb = dpp_xor1(val);
          if (((lane & 1) == 0) && row < N) {
            unsigned pk = f2bf(val) | (f2bf(nb) << 16);
            kvo[(size_t)row * 128 + c + (j == 1 ? 0 : 1)] = pk;
          }
        }
      }
    }
  }
}

// ---------- ONE preprocessing kernel ----------
__global__ void prep(const float* W_in1, const float* W_in2,
                     const float* Wq_n1, const float* Wq_n2,
                     const float* Wa_n1, const float* Wa_n2,
                     const float* Wk_n1, const float* bk_n1,
                     const float* Wv_n1, const float* bv_n1,
                     const float* Wk_n2, const float* bk_n2,
                     const float* Wv_n2, const float* bv_n2,
                     const float* a_rel_12, const float* m_rel_12,
                     const float* a_rel_21, const float* m_rel_21,
                     unsigned* WinT1, unsigned* WinT2,
                     unsigned* WqT1, unsigned* WqT2,
                     unsigned* WaT1, unsigned* WaT2,
                     unsigned* WkT1, float* bkF1, unsigned* WvT1, float* bvF1,
                     unsigned* WkT2, float* bkF2, unsigned* WvT2, float* bvF2,
                     int* deg)
{
  const int yid = blockIdx.y;
  int idx = blockIdx.x * 256 + threadIdx.x;

  if (yid < 10) {
    if (idx >= 8192) return;
    const float* W; unsigned* Wt;
    switch (yid) {
      case 0: W = W_in1;          Wt = WinT1;        break;
      case 1: W = W_in2;          Wt = WinT2;        break;
      case 2: W = Wq_n1;          Wt = WqT1;         break;
      case 3: W = Wq_n1 + 16384;  Wt = WqT1 + 8192;  break;
      case 4: W = Wq_n2;          Wt = WqT2;         break;
      case 5: W = Wq_n2 + 16384;  Wt = WqT2 + 8192;  break;
      case 6: W = Wa_n1;          Wt = WaT1;         break;
      case 7: W = Wa_n1 + 16384;  Wt = WaT1 + 8192;  break;
      case 8: W = Wa_n2;          Wt = WaT2;         break;
      default: W = Wa_n2 + 16384; Wt = WaT2 + 8192;  break;
    }
    int n = idx & 127, kp = idx >> 7;
    float a = W[(size_t)(2 * kp) * 128 + n];
    float b = W[(size_t)(2 * kp + 1) * 128 + n];
    Wt[n * 64 + kp] = f2bf(a) | (f2bf(b) << 16);
  } else if (yid < 18) {
    int job = yid - 10;
    int l = job >> 2, m = job & 3;
    const float *W, *b, *rel; unsigned* Wt; float* bf;
    switch (m) {
      case 0:  W = Wk_n1; b = bk_n1; rel = a_rel_12; Wt = WkT1; bf = bkF1; break;
      case 1:  W = Wv_n1; b = bv_n1; rel = m_rel_12; Wt = WvT1; bf = bvF1; break;
      case 2:  W = Wk_n2; b = bk_n2; rel = a_rel_21; Wt = WkT2; bf = bkF2; break;
      default: W = Wv_n2; b = bv_n2; rel = m_rel_21; Wt = WvT2; bf = bvF2; break;
    }
    W += (size_t)l * 16384; b += l * 128; rel += (size_t)l * 2048;
    Wt += (size_t)l * 8192; bf += l * 128;
    if (idx < 8192) {
      int n = idx & 127, kp = idx >> 7;
      int h = n >> 4, e = n & 15;
      const float* rr = rel + h * 256;
      const float* s0 = W + (size_t)(2 * kp) * 128 + h * 16;
      const float* s1 = s0 + 128;
      float a0 = 0.f, a1 = 0.f;
#pragma unroll
      for (int d = 0; d < 16; ++d) {
        float rv = rr[d * 16 + e];
        a0 = fmaf(s0[d], rv, a0);
        a1 = fmaf(s1[d], rv, a1);
      }
      Wt[n * 64 + kp] = f2bf(a0) | (f2bf(a1) << 16);
    } else if (idx < 8320) {
      int n = idx - 8192;
      int h = n >> 4, e = n & 15;
      const float* rr = rel + h * 256;
      float a = 0.f;
#pragma unroll
      for (int d = 0; d < 16; ++d) a = fmaf(b[h * 16 + d], rr[d * 16 + e], a);
      bf[n] = a;
    }
  } else {
    for (int k = idx; k < 20032; k += 8448) deg[k] = 0;
  }
}

// ---------- CSR build (both graphs) ----------
__global__ void csr_hist2(const int* __restrict__ dst12, const int* __restrict__ dst21,
                          int* __restrict__ deg12, int* __restrict__ deg21)
{
  int e = blockIdx.x * 256 + threadIdx.x;
  if (e < NE12) atomicAdd(&deg12[dst12[e]], 1);
  if (e < NE21) atomicAdd(&deg21[dst21[e]], 1);
}

__global__ void csr_scan2(const int* __restrict__ degA, int* __restrict__ rowptrA,
                          int* __restrict__ cursorA, int NA, int EA,
                          const int* __restrict__ degB, int* __restrict__ rowptrB,
                          int* __restrict__ cursorB, int NB, int EB)
{
  const int* deg = blockIdx.x ? degB : degA;
  int* rowptr = blockIdx.x ? rowptrB : rowptrA;
  int* cursor = blockIdx.x ? cursorB : cursorA;
  const int N = blockIdx.x ? NB : NA;
  const int E = blockIdx.x ? EB : EA;
  __shared__ int part[256];
  const int t = threadIdx.x;
  const int chunk = (N + 255) / 256;
  const int b = t * chunk;
  const int e = (b + chunk < N) ? b + chunk : N;
  int s = 0;
  for (int i = b; i < e; ++i) s += deg[i];
  part[t] = s;
  __syncthreads();
  if (t == 0) {
    int run = 0;
    for (int i = 0; i < 256; ++i) { int v = part[i]; part[i] = run; run += v; }
  }
  __syncthreads();
  int run = part[t];
  for (int i = b; i < e; ++i) { rowptr[i] = run; cursor[i] = run; run += deg[i]; }
  if (t == 0) rowptr[N] = E;
}

// XCD-partitioned scatter: partition = blockIdx.x & 7 (round-robin XCD
// heuristic), chunk = blockIdx.x >> 3. Each partition owns a contiguous dst
// range -> contiguous csr region -> lines written by (heuristically) one XCD's
// L2 only, eliminating cross-XCD partial-line writeback amplification
// (R14: WRITE_SIZE 49.5 MB for 2.56 MB payload). Correct for any mapping.
__global__ void csr_scatter2(const int* __restrict__ src12, const int* __restrict__ dst12,
                             int* __restrict__ cur12, int* __restrict__ csr12,
                             const int* __restrict__ src21, const int* __restrict__ dst21,
                             int* __restrict__ cur21, int* __restrict__ csr21)
{
  const int part = blockIdx.x & 7;
  const int lo = part * 1250, hi = lo + 1250;    // 10000/8 dst nodes per partition
  int e = (blockIdx.x >> 3) * 256 + threadIdx.x;
  if (e < NE12) {
    int d = dst12[e];
    if (d >= lo && d < hi) { int p = atomicAdd(&cur12[d], 1); csr12[p] = src12[e]; }
  }
  if (e < NE21) {
    int d = dst21[e];
    if (d >= lo && d < hi) { int p = atomicAdd(&cur21[d], 1); csr21[p] = src21[e]; }
  }
}

// ---------- fused gather attention (R12's wide-load, static-index version) ----------
__launch_bounds__(256)
__global__ void attn_gather2(const int* __restrict__ rowptr12, const int* __restrict__ csr12,
                             const float* __restrict__ q2, const unsigned* __restrict__ kv1,
                             const float* __restrict__ pr12,
                             const int* __restrict__ rowptr21, const int* __restrict__ csr21,
                             const float* __restrict__ q1, const unsigned* __restrict__ kv2,
                             const float* __restrict__ pr21,
                             float* __restrict__ agg2, float* __restrict__ agg1)
{
  const int wid = (blockIdx.x * 256 + threadIdx.x) >> 6;
  const int lane = threadIdx.x & 63;
  const int sub = lane >> 5;
  const int sl = lane & 31;
  const bool dirB = wid >= PN2;
  const int d = __builtin_amdgcn_readfirstlane(dirB ? wid - PN2 : wid);
  const int* rowptr = dirB ? rowptr21 : rowptr12;
  const int* csr    = dirB ? csr21 : csr12;
  const float* q    = dirB ? q1 : q2;
  const unsigned* kv = dirB ? kv2 : kv1;
  const float* prel = dirB ? pr21 : pr12;
  float* agg = dirB ? agg1 : agg2;

  const int h = sl >> 2;
  const float4 qv = *(const float4*)(q + (size_t)d * 128 + 4 * sl);
  const float pr2 = prel[h] * (0.25f * 1.4426950408889634f);
  const int beg = __builtin_amdgcn_readfirstlane(rowptr[d]);
  const int end = __builtin_amdgcn_readfirstlane(rowptr[d + 1]);
  const int co = 4 * sl;

  float ssum = 0.f, a0 = 0.f, a1 = 0.f, a2 = 0.f, a3 = 0.f;

  uint4 buf[4];
#pragma unroll
  for (int j = 0; j < 4; ++j) {
    int idx = beg + 2 * j + sub;
    int s = (idx < end) ? csr[idx] : 0;
    buf[j] = *(const uint4*)(kv + (size_t)s * 128 + co);
  }

  for (int i = beg; i < end; i += 8) {
    uint4 cur[4];
#pragma unroll
    for (int j = 0; j < 4; ++j) cur[j] = buf[j];
#pragma unroll
    for (int j = 0; j < 4; ++j) {
      int idx = i + 8 + 2 * j + sub;
      int s = (idx < end) ? csr[idx] : 0;
      buf[j] = *(const uint4*)(kv + (size_t)s * 128 + co);
    }
    float p[4], ex[4];
#pragma unroll
    for (int j = 0; j < 4; ++j) {
      float t = qv.x * bf2f(cur[j].x & 0xffffu);
      t = fmaf(qv.y, bf2f(cur[j].x >> 16), t);
      t = fmaf(qv.z, bf2f(cur[j].z & 0xffffu), t);
      p[j] = fmaf(qv.w, bf2f(cur[j].z >> 16), t);
    }
#pragma unroll
    for (int j = 0; j < 4; ++j) p[j] = dpp_red4(p[j]);
#pragma unroll
    for (int j = 0; j < 4; ++j)
      ex[j] = (i + 2 * j + sub < end) ? exp2f(p[j] * pr2) : 0.f;
    ssum += (ex[0] + ex[1]) + (ex[2] + ex[3]);
#pragma unroll
    for (int j = 0; j < 4; ++j) {
      a0 = fmaf(ex[j], bf2f(cur[j].y & 0xffffu), a0);
      a1 = fmaf(ex[j], bf2f(cur[j].y >> 16),     a1);
      a2 = fmaf(ex[j], bf2f(cur[j].w & 0xffffu), a2);
      a3 = fmaf(ex[j], bf2f(cur[j].w >> 16),     a3);
    }
  }

  ssum += __shfl_xor(ssum, 32);
  a0 += __shfl_xor(a0, 32);
  a1 += __shfl_xor(a1, 32);
  a2 += __shfl_xor(a2, 32);
  a3 += __shfl_xor(a3, 32);

  if (sub == 0) {
    const float inv = 1.0f / (ssum + 1e-16f);
    float o0 = a0 * inv, o1 = a1 * inv, o2 = a2 * inv, o3 = a3 * inv;
    o0 = 0.5f * o0 * (1.f + erff(o0 * 0.70710678118654752f));
    o1 = 0.5f * o1 * (1.f + erff(o1 * 0.70710678118654752f));
    o2 = 0.5f * o2 * (1.f + erff(o2 * 0.70710678118654752f));
    o3 = 0.5f * o3 * (1.f + erff(o3 * 0.70710678118654752f));
    float4 out; out.x = o0; out.y = o1; out.z = o2; out.w = o3;
    *(float4*)(agg + (size_t)d * 128 + co) = out;
  }
}

// ---------- readout: 2 edges per 8-lane group, all 16 loads in flight ----------
__launch_bounds__(256)
__global__ void edge_dot_bf(const int* __restrict__ mi, const int* __restrict__ di,
                            const ushort_t* __restrict__ Em, const ushort_t* __restrict__ Ed,
                            float* __restrict__ y, int E)
{
  int t = blockIdx.x * 256 + threadIdx.x;
  int g = t >> 3;
  int gl = t & 7;
  int e0 = 2 * g;
  if (e0 >= E) return;
  const bool has1 = (e0 + 1 < E);
  int m0 = mi[e0], d0 = di[e0];
  int m1 = has1 ? mi[e0 + 1] : m0;
  int d1 = has1 ? di[e0 + 1] : d0;
  const uint4* A0 = (const uint4*)(Em + (size_t)m0 * 256);
  const uint4* B0 = (const uint4*)(Ed + (size_t)d0 * 256);
  const uint4* A1 = (const uint4*)(Em + (size_t)m1 * 256);
  const uint4* B1 = (const uint4*)(Ed + (size_t)d1 * 256);

  uint4 a0[4], b0[4], a1[4], b1[4];
#pragma unroll
  for (int i = 0; i < 4; ++i) { a0[i] = A0[gl + 8 * i]; b0[i] = B0[gl + 8 * i]; }
#pragma unroll
  for (int i = 0; i < 4; ++i) { a1[i] = A1[gl + 8 * i]; b1[i] = B1[gl + 8 * i]; }

  float acc0 = 0.f, acc1 = 0.f;
#pragma unroll
  for (int i = 0; i < 4; ++i) {
    uint4 a = a0[i], b = b0[i];
    acc0 = fmaf(bf2f(a.x & 0xffffu), bf2f(b.x & 0xffffu), acc0);
    acc0 = fmaf(bf2f(a.x >> 16),     bf2f(b.x >> 16),     acc0);
    acc0 = fmaf(bf2f(a.y & 0xffffu), bf2f(b.y & 0xffffu), acc0);
    acc0 = fmaf(bf2f(a.y >> 16),     bf2f(b.y >> 16),     acc0);
    acc0 = fmaf(bf2f(a.z & 0xffffu), bf2f(b.z & 0xffffu), acc0);
    acc0 = fmaf(bf2f(a.z >> 16),     bf2f(b.z >> 16),     acc0);
    acc0 = fmaf(bf2f(a.w & 0xffffu), bf2f(b.w & 0xffffu), acc0);
    acc0 = fmaf(bf2f(a.w >> 16),     bf2f(b.w >> 16),     acc0);
  }
#pragma unroll
  for (int i = 0; i < 4; ++i) {
    uint4 a = a1[i], b = b1[i];
    acc1 = fmaf(bf2f(a.x & 0xffffu), bf2f(b.x & 0xffffu), acc1);
    acc1 = fmaf(bf2f(a.x >> 16),     bf2f(b.x >> 16),     acc1);
    acc1 = fmaf(bf2f(a.y & 0xffffu), bf2f(b.y & 0xffffu), acc1);
    acc1 = fmaf(bf2f(a.y >> 16),     bf2f(b.y >> 16),     acc1);
    acc1 = fmaf(bf2f(a.z & 0xffffu), bf2f(b.z & 0xffffu), acc1);
    acc1 = fmaf(bf2f(a.z >> 16),     bf2f(b.z >> 16),     acc1);
    acc1 = fmaf(bf2f(a.w & 0xffffu), bf2f(b.w & 0xffffu), acc1);
    acc1 = fmaf(bf2f(a.w >> 16),     bf2f(b.w >> 16),     acc1);
  }
  acc0 = dpp_red8(acc0);
  acc1 = dpp_red8(acc1);
  if (gl == 0) {
    y[e0] = acc0;
    if (has1) y[e0 + 1] = acc1;
  }
}

// ---------- launch ----------
extern "C" void kernel_launch(void* const* d_in, const int* in_sizes, int n_in,
                              void* d_out, int out_size, void* d_ws, size_t ws_size,
                              hipStream_t stream)
{
  const float* x_n1  = (const float*)d_in[0];
  const float* x_n2  = (const float*)d_in[1];
  const float* W_in1 = (const float*)d_in[2];
  const float* b_in1 = (const float*)d_in[3];
  const float* W_in2 = (const float*)d_in[4];
  const float* b_in2 = (const float*)d_in[5];
  const float* Wk_n1 = (const float*)d_in[6];
  const float* bk_n1 = (const float*)d_in[7];
  const float* Wq_n1 = (const float*)d_in[8];
  const float* bq_n1 = (const float*)d_in[9];
  const float* Wv_n1 = (const float*)d_in[10];
  const float* bv_n1 = (const float*)d_in[11];
  const float* Wa_n1 = (const float*)d_in[12];
  const float* ba_n1 = (const float*)d_in[13];
  const float* skip_n1 = (const float*)d_in[14];
  const float* Wk_n2 = (const float*)d_in[15];
  const float* bk_n2 = (const float*)d_in[16];
  const float* Wq_n2 = (const float*)d_in[17];
  const float* bq_n2 = (const float*)d_in[18];
  const float* Wv_n2 = (const float*)d_in[19];
  const float* bv_n2 = (const float*)d_in[20];
  const float* Wa_n2 = (const float*)d_in[21];
  const float* ba_n2 = (const float*)d_in[22];
  const float* skip_n2 = (const float*)d_in[23];
  const float* a_rel_12 = (const float*)d_in[24];
  const float* m_rel_12 = (const float*)d_in[25];
  const float* p_rel_12 = (const float*)d_in[26];
  const float* a_rel_21 = (const float*)d_in[27];
  const float* m_rel_21 = (const float*)d_in[28];
  const float* p_rel_21 = (const float*)d_in[29];
  const int*   ei_12 = (const int*)d_in[30];
  const int*   ei_21 = (const int*)d_in[31];
  const int*   edge_index = (const int*)d_in[32];
  float* y = (float*)d_out;

  // ---- workspace carve-up (float units) ----
  const size_t NF = (size_t)PN1 * 128;
  float* ws = (float*)d_ws;
  float* x1   = ws + 0 * NF;
  float* x2   = ws + 1 * NF;
  float* q1   = ws + 2 * NF;
  float* q2   = ws + 3 * NF;
  float* agg1 = ws + 4 * NF;
  float* agg2 = ws + 5 * NF;
  unsigned* kv1 = (unsigned*)(ws + 6 * NF);
  unsigned* kv2 = (unsigned*)(ws + 7 * NF);
  ushort_t* Em  = (ushort_t*)(ws + 8 * NF);
  ushort_t* Ed  = (ushort_t*)(ws + 8 * NF + 1280000);
  unsigned* wb = (unsigned*)(ws + 8 * NF + 2560000);
  unsigned* WkT1 = wb;                     float* bkF1 = (float*)(wb + 16384);
  unsigned* WvT1 = wb + 16640;             float* bvF1 = (float*)(wb + 33024);
  unsigned* WkT2 = wb + 33280;             float* bkF2 = (float*)(wb + 49664);
  unsigned* WvT2 = wb + 49920;             float* bvF2 = (float*)(wb + 66304);
  unsigned* WinT1 = wb + 66560;
  unsigned* WinT2 = wb + 74752;
  unsigned* WqT1  = wb + 82944;
  unsigned* WqT2  = wb + 99328;
  unsigned* WaT1  = wb + 115712;
  unsigned* WaT2  = wb + 132096;
  int* ip = (int*)(wb + 148480);
  int* rowptr12 = ip;
  int* rowptr21 = ip + 10016;
  int* cur12    = ip + 20032;
  int* cur21    = ip + 30048;
  int* deg12    = ip + 40064;
  int* deg21    = ip + 50080;
  int* csr12    = ip + 60096;
  int* csr21    = ip + 60096 + NE12;

  const int EB = (NE12 + 255) / 256;   // 1250

  // ---- one preprocessing dispatch ----
  prep<<<dim3(33, 19), 256, 0, stream>>>(
      W_in1, W_in2, Wq_n1, Wq_n2, Wa_n1, Wa_n2,
      Wk_n1, bk_n1, Wv_n1, bv_n1, Wk_n2, bk_n2, Wv_n2, bv_n2,
      a_rel_12, m_rel_12, a_rel_21, m_rel_21,
      WinT1, WinT2, WqT1, WqT2, WaT1, WaT2,
      WkT1, bkF1, WvT1, bvF1, WkT2, bkF2, WvT2, bvF2, deg12);

  // ---- CSR build (XCD-partitioned scatter) ----
  csr_hist2<<<EB, 256, 0, stream>>>(ei_12 + NE12, ei_21 + NE21, deg12, deg21);
  csr_scan2<<<2, 256, 0, stream>>>(deg12, rowptr12, cur12, PN2, NE12,
                                   deg21, rowptr21, cur21, PN1, NE21);
  csr_scatter2<<<EB * 8, 256, 0, stream>>>(ei_12, ei_12 + NE12, cur12, csr12,
                                           ei_21, ei_21 + NE21, cur21, csr21);

  // ---- input projections + relu ----
  mfma_gemm1<<<2 * GB, 256, 0, stream>>>(x_n1, x_n2, WinT1, b_in1, WinT2, b_in2,
                                         x1, x2, GB, PN1, 0,
                                         nullptr, nullptr, nullptr, nullptr, 0);

  for (int l = 0; l < NLAY; ++l) {
    const int bo = l * 128;
    mfma_kvq<<<2 * GB, 256, 0, stream>>>(
        x1, x2,
        WqT1 + (size_t)l * 8192, WkT1 + (size_t)l * 8192, WvT1 + (size_t)l * 8192,
        bq_n1 + bo, bkF1 + bo, bvF1 + bo,
        WqT2 + (size_t)l * 8192, WkT2 + (size_t)l * 8192, WvT2 + (size_t)l * 8192,
        bq_n2 + bo, bkF2 + bo, bvF2 + bo,
        q1, kv1, q2, kv2, GB, PN1);

    attn_gather2<<<(2 * PN1) / 4, 256, 0, stream>>>(
        rowptr12, csr12, q2, kv1, p_rel_12 + l * NH,
        rowptr21, csr21, q1, kv2, p_rel_21 + l * NH,
        agg2, agg1);

    mfma_gemm1<<<2 * GB, 256, 0, stream>>>(
        agg1, agg2, WaT1 + (size_t)l * 8192, ba_n1 + bo,
        WaT2 + (size_t)l * 8192, ba_n2 + bo,
        x1, x2, GB, PN1, 2, skip_n1 + l, skip_n2 + l, Em, Ed, bo);
  }

  // ---- readout: 2 edges per 8-lane group ----
  const int DOT_B = (((NEF + 1) / 2) * 8 + 255) / 256;   // 7813
  edge_dot_bf<<<DOT_B, 256, 0, stream>>>(edge_index, edge_index + NEF, Em, Ed, y, NEF);
}